// Round 9
// baseline (525.006 us; speedup 1.0000x reference)
//
#include <hip/hip_runtime.h>
#include <math.h>

// kNN (B=1024, C=500000, D=64) + inverse-distance weighting, top-50.
// R9: filter = R5 shape (512 thr, 2 query passes, no spill) + R8 tech
// (pre-swizzled bf16 table, async global_load_lds width-16, dbuf 64-row
// stages). LDS 38 KB -> 4 blocks/CU so barrier stalls overlap.
// qthresh = clean 4-queries/block (sample streamed once per 4 queries).
// select = R6/R7. Fallback (R5 filter) if workspace too small.

#define DELTA_SMOOTH 1e-3f
#define K_NEIGH 50
#define MAXCAP 8192
#define SAMPLE 2048
#define SAMPLE_TARGET 6
#define NBINS 256
#define MARGIN 0.75f       // bf16 dot worst-case error margin (d2 units)
#define MARGIN_Q 26        // select margin in d2q quanta: 2*(0.75+1/16)*16
#define RPB 1024           // table rows per filter block
#define QTILE 512          // queries per filter block (8 waves x 64)
#define SDEPTH 6           // LDS staging slots per (block,query); lambda~3
#define LW 768             // select rescore list size
#define CVL 4096           // select LDS candidate cache
#define QB 4               // queries per qthresh block

typedef __attribute__((ext_vector_type(8))) short short8;
typedef __attribute__((ext_vector_type(4))) float f32x4;
typedef __attribute__((address_space(1))) const unsigned int g_u32;
typedef __attribute__((address_space(3))) unsigned int l_u32;

__device__ __forceinline__ unsigned f2bf(float f) {
  unsigned u = __float_as_uint(f);
  return ((u + 0x7fffu + ((u >> 16) & 1u)) >> 16) & 0xffffu;
}

// ---------------- Kernel 0: table -> bf16 swizzled 64-row tiles + halved norms ----------------
// Row r chunk c (8 bf16 = 16 B) at uint4 index (r>>6)*512 + (r&63)*8 + (c^(r&7)).
// A 64-row tile = contiguous 8 KB whose byte image IS the LDS stage layout.
__global__ __launch_bounds__(256) void convert_kernel(
    const float* __restrict__ tk, uint4* __restrict__ tkbf,
    float* __restrict__ tnh2, int C, int padded) {
  int t = blockIdx.x * 256 + threadIdx.x;   // (row, chunk) id
  int r = t >> 3;
  if (r >= padded) return;
  int c = t & 7;
  int rs = r < C ? r : C - 1;
  const float4* src = (const float4*)(tk + (size_t)rs * 64 + c * 8);
  float4 a = src[0], b = src[1];
  float sq = a.x * a.x + a.y * a.y + a.z * a.z + a.w * a.w
           + b.x * b.x + b.y * b.y + b.z * b.z + b.w * b.w;
  sq += __shfl_xor(sq, 1); sq += __shfl_xor(sq, 2); sq += __shfl_xor(sq, 4);
  if (c == 0) tnh2[r] = sq * 0.5f;
  uint4 u;
  u.x = f2bf(a.x) | (f2bf(a.y) << 16);
  u.y = f2bf(a.z) | (f2bf(a.w) << 16);
  u.z = f2bf(b.x) | (f2bf(b.y) << 16);
  u.w = f2bf(b.z) | (f2bf(b.w) << 16);
  tkbf[(size_t)(r >> 6) * 512 + (r & 63) * 8 + (c ^ (r & 7))] = u;
}

// ---------------- Kernel 1: per-query radius, 4 queries/block ----------------
// Each block streams the 2048-row sample ONCE and dots it against 4 query
// vectors held in registers (4 lanes cooperate per row).
__global__ __launch_bounds__(256) void qthresh_kernel(
    const float* __restrict__ keys, const float* __restrict__ tk,
    float* __restrict__ thr, float* __restrict__ qnorm, int C) {
  int q0 = blockIdx.x * QB;
  __shared__ __align__(16) float kq[QB * 64];
  __shared__ unsigned hist[QB][NBINS];
  __shared__ float qn4[QB];
  int tid = threadIdx.x;
  for (int i = tid; i < QB * 64; i += 256) kq[i] = keys[(size_t)q0 * 64 + i];
  for (int i = tid; i < QB * NBINS; i += 256) (&hist[0][0])[i] = 0u;
  __syncthreads();
  if (tid < QB) {
    float s = 0.f;
    for (int j = 0; j < 64; ++j) { float v = kq[tid * 64 + j]; s += v * v; }
    qn4[tid] = s;
  }
  __syncthreads();
  int kc = tid & 3;                 // quarter of the row this lane handles
  const float4* kq4 = (const float4*)kq;
  float4 kf[QB][4];
  #pragma unroll
  for (int jq = 0; jq < QB; ++jq)
    #pragma unroll
    for (int u = 0; u < 4; ++u) kf[jq][u] = kq4[jq * 16 + kc * 4 + u];
  int S = SAMPLE < C ? SAMPLE : C;
  for (int r = tid >> 2; r < S; r += 64) {
    const float4* trow = (const float4*)(tk + (size_t)r * 64 + kc * 16);
    float4 t0 = trow[0], t1 = trow[1], t2 = trow[2], t3 = trow[3];
    float tn = t0.x * t0.x + t0.y * t0.y + t0.z * t0.z + t0.w * t0.w
             + t1.x * t1.x + t1.y * t1.y + t1.z * t1.z + t1.w * t1.w
             + t2.x * t2.x + t2.y * t2.y + t2.z * t2.z + t2.w * t2.w
             + t3.x * t3.x + t3.y * t3.y + t3.z * t3.z + t3.w * t3.w;
    tn += __shfl_xor(tn, 1); tn += __shfl_xor(tn, 2);
    float dot[QB];
    #pragma unroll
    for (int jq = 0; jq < QB; ++jq) {
      float s = kf[jq][0].x * t0.x + kf[jq][0].y * t0.y + kf[jq][0].z * t0.z + kf[jq][0].w * t0.w
              + kf[jq][1].x * t1.x + kf[jq][1].y * t1.y + kf[jq][1].z * t1.z + kf[jq][1].w * t1.w
              + kf[jq][2].x * t2.x + kf[jq][2].y * t2.y + kf[jq][2].z * t2.z + kf[jq][2].w * t2.w
              + kf[jq][3].x * t3.x + kf[jq][3].y * t3.y + kf[jq][3].z * t3.z + kf[jq][3].w * t3.w;
      s += __shfl_xor(s, 1); s += __shfl_xor(s, 2);
      dot[jq] = s;
    }
    if (kc == 0) {
      #pragma unroll
      for (int jq = 0; jq < QB; ++jq) {
        float d2 = qn4[jq] + tn - 2.f * dot[jq];
        int b = (int)d2;
        b = b < 0 ? 0 : (b > NBINS - 1 ? NBINS - 1 : b);
        atomicAdd(&hist[jq][b], 1u);
      }
    }
  }
  __syncthreads();
  if (tid < QB) {
    unsigned cum = 0; int bstar = NBINS - 1;
    for (int b = 0; b < NBINS; ++b) {
      cum += hist[tid][b];
      if (cum >= (unsigned)SAMPLE_TARGET) { bstar = b; break; }
    }
    thr[q0 + tid] = (float)(bstar + 1) + MARGIN - qn4[tid];
    qnorm[q0 + tid] = qn4[tid];
  }
}

// ---------------- Kernel 2a: async-staged bf16 MFMA filter (no-spill shape) ----------------
// 8 waves x 64 queries; 64-row DMA stages (8 KB), dbuf, 1 barrier/stage.
// hit <=> tnh - acc < thr/2 (hmax precheck in regs, thr_lds in rare path).
__global__ __launch_bounds__(512, 4) void filter_mfma_fast(
    const uint4* __restrict__ tkbf, const float* __restrict__ keys,
    const float* __restrict__ tnh2, const float* __restrict__ thr,
    const float* __restrict__ qnorm, int* __restrict__ cnt,
    unsigned* __restrict__ candi, int C, int cap) {
  __shared__ __align__(16) uint4 bstage[2][512];          // 16 KB dbuf
  __shared__ float tnh_lds[RPB];                          // 4 KB (halved norms)
  __shared__ float thr_lds[QTILE];                        // 2 KB
  __shared__ float qn_lds[QTILE];                         // 2 KB
  __shared__ unsigned scnt[QTILE];                        // 2 KB
  __shared__ unsigned sbuf[QTILE * SDEPTH];               // 12 KB

  int tid = threadIdx.x;
  int qt = blockIdx.x & 1;
  int chunk = blockIdx.x >> 1;
  int qbase = qt * QTILE;
  int rstart = chunk * RPB;

  tnh_lds[tid] = tnh2[rstart + tid];
  tnh_lds[tid + 512] = tnh2[rstart + tid + 512];
  thr_lds[tid] = thr[qbase + tid];
  qn_lds[tid] = qnorm[qbase + tid];
  scnt[tid] = 0u;

  int lane = tid & 63;
  int wq = tid >> 6;       // 0..7
  int l15 = lane & 15;
  int quad = lane >> 4;

  // A fragments: 4 m-tiles; A[m=l15][k=s*32+quad*8+j] (verified R2-R8)
  short8 afrag[4][2];
  #pragma unroll
  for (int mt = 0; mt < 4; ++mt) {
    const float* kp = keys + (size_t)(qbase + wq * 64 + mt * 16 + l15) * 64 + quad * 8;
    #pragma unroll
    for (int s = 0; s < 2; ++s) {
      float4 x = *(const float4*)(kp + s * 32);
      float4 y = *(const float4*)(kp + s * 32 + 4);
      short8 a;
      a[0] = (short)f2bf(x.x); a[1] = (short)f2bf(x.y);
      a[2] = (short)f2bf(x.z); a[3] = (short)f2bf(x.w);
      a[4] = (short)f2bf(y.x); a[5] = (short)f2bf(y.y);
      a[6] = (short)f2bf(y.z); a[7] = (short)f2bf(y.w);
      afrag[mt][s] = a;
    }
  }

  // stage 0 DMA: wave-uniform LDS base + lane*16
  const uint4* gbase = tkbf + (size_t)(rstart >> 6) * 512;
  __builtin_amdgcn_global_load_lds((g_u32*)(gbase + tid),
                                   (l_u32*)(&bstage[0][wq * 64]), 16, 0, 0);
  __syncthreads();   // drains stage-0 DMA + publishes shared preloads

  // halved quad-max thresholds in regs (exact thr from LDS in rare path)
  float hmax[4];
  #pragma unroll
  for (int mt = 0; mt < 4; ++mt) {
    float h0 = thr_lds[wq * 64 + mt * 16 + quad * 4 + 0];
    float h1 = thr_lds[wq * 64 + mt * 16 + quad * 4 + 1];
    float h2 = thr_lds[wq * 64 + mt * 16 + quad * 4 + 2];
    float h3 = thr_lds[wq * 64 + mt * 16 + quad * 4 + 3];
    hmax[mt] = fmaxf(fmaxf(h0, h1), fmaxf(h2, h3)) * 0.5f;
  }

  f32x4 zero4 = {0.f, 0.f, 0.f, 0.f};
  const int ITERS = RPB / 64;   // 16

  for (int it = 0; it < ITERS; ++it) {
    if (it + 1 < ITERS) {
      __builtin_amdgcn_global_load_lds((g_u32*)(gbase + (size_t)(it + 1) * 512 + tid),
                                       (l_u32*)(&bstage[(it + 1) & 1][wq * 64]), 16, 0, 0);
    }
    const unsigned char* buf = (const unsigned char*)bstage[it & 1];
    #pragma unroll
    for (int half = 0; half < 2; ++half) {
      // B fragments: row nloc, chunk c=s*4+quad, swizzled byte address
      short8 b[2][2];
      #pragma unroll
      for (int tt = 0; tt < 2; ++tt) {
        int nloc = half * 32 + tt * 16 + l15;
        #pragma unroll
        for (int s = 0; s < 2; ++s) {
          int c = s * 4 + quad;
          unsigned addr = (unsigned)(nloc * 128 + ((c ^ (nloc & 7)) << 4));
          b[tt][s] = *(const short8*)(buf + addr);
        }
      }
      f32x4 acc[4][2];
      #pragma unroll
      for (int mt = 0; mt < 4; ++mt) {
        #pragma unroll
        for (int tt = 0; tt < 2; ++tt) {
          f32x4 a0 = __builtin_amdgcn_mfma_f32_16x16x32_bf16(afrag[mt][0], b[tt][0], zero4, 0, 0, 0);
          acc[mt][tt] = __builtin_amdgcn_mfma_f32_16x16x32_bf16(afrag[mt][1], b[tt][1], a0, 0, 0, 0);
        }
      }
      #pragma unroll
      for (int tt = 0; tt < 2; ++tt) {
        int rloc = it * 64 + half * 32 + tt * 16 + l15;
        float tnh = tnh_lds[rloc];
        int n = rstart + rloc;
        #pragma unroll
        for (int mt = 0; mt < 4; ++mt) {
          float mx4 = fmaxf(fmaxf(acc[mt][tt][0], acc[mt][tt][1]),
                            fmaxf(acc[mt][tt][2], acc[mt][tt][3]));
          if (mx4 + hmax[mt] > tnh) {
            #pragma unroll
            for (int r = 0; r < 4; ++r) {
              int ql = wq * 64 + mt * 16 + quad * 4 + r;
              // tnh - acc < thr/2  <=>  d2' < thr
              if (tnh - acc[mt][tt][r] < 0.5f * thr_lds[ql] && n < C) {
                float d2f = 2.f * (tnh - acc[mt][tt][r]) + qn_lds[ql];
                int d2q = (int)(d2f * 16.f);
                d2q = d2q < 0 ? 0 : (d2q > 8191 ? 8191 : d2q);
                unsigned v = ((unsigned)d2q << 19) | (unsigned)n;
                unsigned p = atomicAdd(&scnt[ql], 1u);
                if (p < SDEPTH) {
                  sbuf[ql * SDEPTH + p] = v;
                } else {
                  int g = atomicAdd(&cnt[qbase + ql], 1);
                  if (g < cap) candi[(size_t)(qbase + ql) * cap + g] = v;
                }
              }
            }
          }
        }
      }
    }
    __syncthreads();   // drains prefetch DMA; safe buffer swap
  }
  // flush: one global atomic per (block, query)
  int m = (int)scnt[tid];
  if (m > SDEPTH) m = SDEPTH;
  if (m > 0) {
    int base = atomicAdd(&cnt[qbase + tid], m);
    for (int j = 0; j < m; ++j) {
      int g = base + j;
      if (g < cap) candi[(size_t)(qbase + tid) * cap + g] = sbuf[tid * SDEPTH + j];
    }
  }
}

// ---------------- Kernel 2b: FALLBACK filter (R5 verbatim; in-loop convert) ----------------
__global__ __launch_bounds__(512, 4) void filter_fallback(
    const float* __restrict__ keys, const float* __restrict__ tk,
    const float* __restrict__ thr, const float* __restrict__ qnorm,
    int* __restrict__ cnt, unsigned* __restrict__ candi, int C, int cap) {
  __shared__ float tnstage[64];
  __shared__ float thr_lds[QTILE];
  __shared__ float qn_lds[QTILE];
  __shared__ unsigned scnt[QTILE];
  __shared__ unsigned sbuf[QTILE * SDEPTH];
  __shared__ __align__(16) unsigned char bstage[64 * 128];

  int tid = threadIdx.x;
  int qt = blockIdx.x & 1;
  int chunk = blockIdx.x >> 1;
  int qbase = qt * QTILE;
  int rstart = chunk * RPB;

  thr_lds[tid] = thr[qbase + tid];
  qn_lds[tid] = qnorm[qbase + tid];
  scnt[tid] = 0u;

  int lane = tid & 63;
  int wq = tid >> 6;
  int l15 = lane & 15;
  int quad = lane >> 4;

  short8 afrag[4][2];
  #pragma unroll
  for (int mt = 0; mt < 4; ++mt) {
    const float* kp = keys + (size_t)(qbase + wq * 64 + mt * 16 + l15) * 64 + quad * 8;
    #pragma unroll
    for (int s = 0; s < 2; ++s) {
      float4 x = *(const float4*)(kp + s * 32);
      float4 y = *(const float4*)(kp + s * 32 + 4);
      short8 a;
      a[0] = (short)f2bf(x.x); a[1] = (short)f2bf(x.y);
      a[2] = (short)f2bf(x.z); a[3] = (short)f2bf(x.w);
      a[4] = (short)f2bf(y.x); a[5] = (short)f2bf(y.y);
      a[6] = (short)f2bf(y.z); a[7] = (short)f2bf(y.w);
      afrag[mt][s] = a;
    }
  }
  __syncthreads();

  float hq[4];
  #pragma unroll
  for (int mt = 0; mt < 4; ++mt) {
    float h0 = thr_lds[wq * 64 + mt * 16 + quad * 4 + 0];
    float h1 = thr_lds[wq * 64 + mt * 16 + quad * 4 + 1];
    float h2 = thr_lds[wq * 64 + mt * 16 + quad * 4 + 2];
    float h3 = thr_lds[wq * 64 + mt * 16 + quad * 4 + 3];
    hq[mt] = fmaxf(fmaxf(h0, h1), fmaxf(h2, h3));
  }

  int srow = tid >> 3;
  int scol = tid & 7;
  unsigned sbyte = (unsigned)(srow * 128 + ((scol ^ (srow & 7)) << 4));

  const int ITERS = RPB / 64;
  int r0 = rstart + srow; if (r0 > C - 1) r0 = C - 1;
  float4 pa = *(const float4*)(tk + (size_t)r0 * 64 + scol * 8);
  float4 pb = *(const float4*)(tk + (size_t)r0 * 64 + scol * 8 + 4);

  f32x4 zero4 = {0.f, 0.f, 0.f, 0.f};

  for (int it = 0; it < ITERS; ++it) {
    float part = pa.x * pa.x + pa.y * pa.y + pa.z * pa.z + pa.w * pa.w
               + pb.x * pb.x + pb.y * pb.y + pb.z * pb.z + pb.w * pb.w;
    part += __shfl_xor(part, 1);
    part += __shfl_xor(part, 2);
    part += __shfl_xor(part, 4);
    if ((tid & 7) == 0) tnstage[srow] = part;
    uint4 u;
    u.x = f2bf(pa.x) | (f2bf(pa.y) << 16);
    u.y = f2bf(pa.z) | (f2bf(pa.w) << 16);
    u.z = f2bf(pb.x) | (f2bf(pb.y) << 16);
    u.w = f2bf(pb.z) | (f2bf(pb.w) << 16);
    *(uint4*)(bstage + sbyte) = u;
    __syncthreads();
    if (it + 1 < ITERS) {
      int rn = rstart + (it + 1) * 64 + srow; if (rn > C - 1) rn = C - 1;
      pa = *(const float4*)(tk + (size_t)rn * 64 + scol * 8);
      pb = *(const float4*)(tk + (size_t)rn * 64 + scol * 8 + 4);
    }
    #pragma unroll
    for (int half = 0; half < 2; ++half) {
      short8 b[2][2];
      #pragma unroll
      for (int tt = 0; tt < 2; ++tt) {
        int nloc = half * 32 + tt * 16 + l15;
        #pragma unroll
        for (int s = 0; s < 2; ++s) {
          int c = s * 4 + quad;
          unsigned addr = (unsigned)(nloc * 128 + ((c ^ (nloc & 7)) << 4));
          b[tt][s] = *(const short8*)(bstage + addr);
        }
      }
      f32x4 acc[4][2];
      #pragma unroll
      for (int mt = 0; mt < 4; ++mt) {
        #pragma unroll
        for (int tt = 0; tt < 2; ++tt) {
          f32x4 a0 = __builtin_amdgcn_mfma_f32_16x16x32_bf16(afrag[mt][0], b[tt][0], zero4, 0, 0, 0);
          acc[mt][tt] = __builtin_amdgcn_mfma_f32_16x16x32_bf16(afrag[mt][1], b[tt][1], a0, 0, 0, 0);
        }
      }
      #pragma unroll
      for (int tt = 0; tt < 2; ++tt) {
        float tn = tnstage[half * 32 + tt * 16 + l15];
        int n = rstart + it * 64 + half * 32 + tt * 16 + l15;
        #pragma unroll
        for (int mt = 0; mt < 4; ++mt) {
          float d0 = fmaf(-2.f, acc[mt][tt][0], tn);
          float d1 = fmaf(-2.f, acc[mt][tt][1], tn);
          float d2 = fmaf(-2.f, acc[mt][tt][2], tn);
          float d3 = fmaf(-2.f, acc[mt][tt][3], tn);
          float mn4 = fminf(fminf(d0, d1), fminf(d2, d3));
          if (mn4 < hq[mt]) {
            float dd[4] = {d0, d1, d2, d3};
            #pragma unroll
            for (int r = 0; r < 4; ++r) {
              int ql = wq * 64 + mt * 16 + quad * 4 + r;
              if (dd[r] < thr_lds[ql] && n < C) {
                float d2f = dd[r] + qn_lds[ql];
                int d2q = (int)(d2f * 16.f);
                d2q = d2q < 0 ? 0 : (d2q > 8191 ? 8191 : d2q);
                unsigned v = ((unsigned)d2q << 19) | (unsigned)n;
                unsigned p = atomicAdd(&scnt[ql], 1u);
                if (p < SDEPTH) {
                  sbuf[ql * SDEPTH + p] = v;
                } else {
                  int g = atomicAdd(&cnt[qbase + ql], 1);
                  if (g < cap) candi[(size_t)(qbase + ql) * cap + g] = v;
                }
              }
            }
          }
        }
      }
    }
    __syncthreads();
  }
  int m = (int)scnt[tid];
  if (m > SDEPTH) m = SDEPTH;
  if (m > 0) {
    int base = atomicAdd(&cnt[qbase + tid], m);
    for (int j = 0; j < m; ++j) {
      int g = base + j;
      if (g < cap) candi[(size_t)(qbase + tid) * cap + g] = sbuf[tid * SDEPTH + j];
    }
  }
}

// ---------------- Kernel 3: select (LDS-cached list; R6/R7 version) ----------------
__global__ __launch_bounds__(256) void select_kernel(
    const float* __restrict__ keys, const float* __restrict__ tk,
    const float* __restrict__ tv, const int* __restrict__ cnt,
    const unsigned* __restrict__ candi, float* __restrict__ out, int cap) {
  int q = blockIdx.x;
  __shared__ unsigned cvl[CVL];
  __shared__ unsigned hist[NBINS];
  __shared__ unsigned wsum[4];
  __shared__ unsigned minq_sh;
  __shared__ int b50_sh;
  __shared__ int lidx[LW];
  __shared__ unsigned ed2[LW];
  __shared__ int m_sh;
  __shared__ float redw[4], redwv[4];
  int tid = threadIdx.x;
  int lane = tid & 63;
  int wid = tid >> 6;
  int n = cnt[q];
  if (n > cap) n = cap;
  hist[tid] = 0u;
  if (tid == 0) { minq_sh = 0xffffffffu; b50_sh = NBINS - 1; m_sh = 0; }
  __syncthreads();
  const unsigned* cv = candi + (size_t)q * cap;
  unsigned mn = 0xffffffffu;
  for (int i = tid; i < n; i += 256) {
    unsigned v = cv[i];
    if (i < CVL) cvl[i] = v;
    unsigned d = v >> 19; if (d < mn) mn = d;
  }
  #pragma unroll
  for (int off = 1; off < 64; off <<= 1) { unsigned o = __shfl_xor(mn, off); if (o < mn) mn = o; }
  if (lane == 0) atomicMin(&minq_sh, mn);
  __syncthreads();
  unsigned base = minq_sh;
  for (int i = tid; i < n; i += 256) {
    unsigned v = (i < CVL) ? cvl[i] : cv[i];
    unsigned d = (v >> 19) - base;
    unsigned b = d >> 1; if (b > NBINS - 1) b = NBINS - 1;
    atomicAdd(&hist[b], 1u);
  }
  __syncthreads();
  unsigned h = hist[tid];
  unsigned p = h;
  #pragma unroll
  for (int off = 1; off < 64; off <<= 1) {
    unsigned v = __shfl_up(p, off);
    if (lane >= off) p += v;
  }
  if (lane == 63) wsum[wid] = p;
  __syncthreads();
  unsigned add = 0;
  for (int w2 = 0; w2 < wid; ++w2) add += wsum[w2];
  p += add;
  if (p >= (unsigned)K_NEIGH && p - h < (unsigned)K_NEIGH) b50_sh = tid;
  __syncthreads();
  unsigned Tq = base + (((unsigned)(b50_sh + 1)) << 1) + MARGIN_Q;
  for (int i = tid; i < n; i += 256) {
    unsigned v = (i < CVL) ? cvl[i] : cv[i];
    if ((v >> 19) <= Tq) {
      int p2 = atomicAdd(&m_sh, 1);
      if (p2 < LW) lidx[p2] = (int)(v & 0x7ffffu);
    }
  }
  __syncthreads();
  int m = m_sh; if (m > LW) m = LW;
  float kqv = keys[(size_t)q * 64 + lane];
  for (int i0 = wid * 4; i0 < m; i0 += 16) {
    int mm = m - i0; if (mm > 4) mm = 4;
    int idx[4]; float t[4];
    for (int u = 0; u < mm; ++u) idx[u] = lidx[i0 + u];
    for (int u = 0; u < mm; ++u) t[u] = tk[(size_t)idx[u] * 64 + lane];
    for (int u = 0; u < mm; ++u) {
      float d = t[u] - kqv;
      float s = d * d;
      #pragma unroll
      for (int off = 1; off < 64; off <<= 1) s += __shfl_xor(s, off);
      if (lane == 0) ed2[i0 + u] = __float_as_uint(s);
    }
  }
  __syncthreads();
  float accw = 0.f, accwv = 0.f;
  for (int i = tid; i < m; i += 256) {
    unsigned long long key = ((unsigned long long)ed2[i] << 19) | (unsigned)lidx[i];
    int rank = 0;
    for (int j = 0; j < m; ++j) {
      unsigned long long kj = ((unsigned long long)ed2[j] << 19) | (unsigned)lidx[j];
      rank += (kj < key) ? 1 : 0;
    }
    if (rank < K_NEIGH) {
      float d2 = __uint_as_float(ed2[i]);
      float w = 1.f / (d2 + DELTA_SMOOTH);
      accw += w;
      accwv += w * tv[lidx[i]];
    }
  }
  #pragma unroll
  for (int off = 1; off < 64; off <<= 1) {
    accw += __shfl_xor(accw, off);
    accwv += __shfl_xor(accwv, off);
  }
  if (lane == 0) { redw[wid] = accw; redwv[wid] = accwv; }
  __syncthreads();
  if (tid == 0) {
    float sw = redw[0] + redw[1] + redw[2] + redw[3];
    float swv = redwv[0] + redwv[1] + redwv[2] + redwv[3];
    out[q] = swv / sw;
  }
}

extern "C" void kernel_launch(void* const* d_in, const int* in_sizes, int n_in,
                              void* d_out, int out_size, void* d_ws, size_t ws_size,
                              hipStream_t stream) {
  const float* keys = (const float*)d_in[0];   // [B,64]
  const float* tk   = (const float*)d_in[1];   // [C,64]
  const float* tv   = (const float*)d_in[2];   // [C]
  float* out = (float*)d_out;
  int B = in_sizes[0] / 64;   // 1024
  int C = in_sizes[2];        // 500000 (< 2^19 for packing)

  int nchunks = (C + RPB - 1) / RPB;   // 489
  int padded = nchunks * RPB;

  char* w = (char*)d_ws;
  float* thr = (float*)w;  w += (size_t)B * 4;
  float* qn  = (float*)w;  w += (size_t)B * 4;
  int*   cnt = (int*)w;    w += (size_t)B * 4;

  size_t fixed = (size_t)(w - (char*)d_ws);
  size_t fast_need = fixed + (size_t)padded * 128 + (size_t)padded * 4
                   + 2048ull * (size_t)B * 4;
  bool fast = ws_size >= fast_need;

  hipMemsetAsync(cnt, 0, (size_t)B * 4, stream);
  qthresh_kernel<<<B / QB, 256, 0, stream>>>(keys, tk, thr, qn, C);

  if (fast) {
    uint4* tkbf  = (uint4*)w;             w += (size_t)padded * 128;
    float* tnh2  = (float*)w;             w += (size_t)padded * 4;
    size_t used = (size_t)(w - (char*)d_ws);
    int cap = (int)((ws_size - used) / (4ull * (size_t)B));
    if (cap > MAXCAP) cap = MAXCAP;
    unsigned* candi = (unsigned*)w;
    convert_kernel<<<padded / 32, 256, 0, stream>>>(tk, tkbf, tnh2, C, padded);
    filter_mfma_fast<<<nchunks * 2, 512, 0, stream>>>(tkbf, keys, tnh2, thr, qn,
                                                      cnt, candi, C, cap);
    select_kernel<<<B, 256, 0, stream>>>(keys, tk, tv, cnt, candi, out, cap);
  } else {
    int cap = (int)((ws_size - fixed) / (4ull * (size_t)B));
    if (cap > MAXCAP) cap = MAXCAP;
    if (cap < 1) cap = 1;
    unsigned* candi = (unsigned*)w;
    filter_fallback<<<nchunks * 2, 512, 0, stream>>>(keys, tk, thr, qn,
                                                     cnt, candi, C, cap);
    select_kernel<<<B, 256, 0, stream>>>(keys, tk, tv, cnt, candi, out, cap);
  }
}

// Round 10
// 448.320 us; speedup vs baseline: 1.1711x; 1.1711x over previous
//
#include <hip/hip_runtime.h>
#include <math.h>

// kNN (B=1024, C=500000, D=64) + inverse-distance weighting, top-50.
// R10: tighter threshold via MFMA-sampled exact quantiles (16384 rows, T=13
// -> ~520 candidates/query instead of 1465); qn eliminated (per-query
// ordering is qn-invariant). Filter = R9 no-spill DMA shape with cheaper
// epilogue. dsamp aliases candi (sequential lifetimes). Fallback chain kept.

#define DELTA_SMOOTH 1e-3f
#define K_NEIGH 50
#define MAXCAP 8192
#define NBINS 256
#define MARGIN_T 1.5f      // bf16 dot error margin, both directions (d2 units)
#define MARGIN_Q 26        // select margin in d2q quanta (16 per d2 unit)
#define RPB 1024           // table rows per filter block
#define QTILE 512          // queries per filter block (8 waves x 64)
#define SDEPTH 6           // LDS staging slots per (block,query); lambda~1.1
#define LW 768             // select rescore list size
#define CVL 2048           // select LDS candidate cache
#define S_SAMP 16384       // qthresh sample rows
#define T_SAMP 13          // order statistic -> E[count] ~ 397
// fallback (R5/R9-style) constants
#define FSAMPLE 2048
#define FTARGET 6
#define FMARGIN 0.75f
#define FQB 4

typedef __attribute__((ext_vector_type(8))) short short8;
typedef __attribute__((ext_vector_type(4))) float f32x4;
typedef __attribute__((address_space(1))) const unsigned int g_u32;
typedef __attribute__((address_space(3))) unsigned int l_u32;

__device__ __forceinline__ unsigned f2bf(float f) {
  unsigned u = __float_as_uint(f);
  return ((u + 0x7fffu + ((u >> 16) & 1u)) >> 16) & 0xffffu;
}

// ---------------- Kernel 0: table -> bf16 swizzled 64-row tiles + halved norms ----------------
// Row r chunk c (8 bf16 = 16 B) at uint4 index (r>>6)*512 + (r&63)*8 + (c^(r&7)).
__global__ __launch_bounds__(256) void convert_kernel(
    const float* __restrict__ tk, uint4* __restrict__ tkbf,
    float* __restrict__ tnh2, int C, int padded) {
  int t = blockIdx.x * 256 + threadIdx.x;
  int r = t >> 3;
  if (r >= padded) return;
  int c = t & 7;
  int rs = r < C ? r : C - 1;
  const float4* src = (const float4*)(tk + (size_t)rs * 64 + c * 8);
  float4 a = src[0], b = src[1];
  float sq = a.x * a.x + a.y * a.y + a.z * a.z + a.w * a.w
           + b.x * b.x + b.y * b.y + b.z * b.z + b.w * b.w;
  sq += __shfl_xor(sq, 1); sq += __shfl_xor(sq, 2); sq += __shfl_xor(sq, 4);
  if (c == 0) tnh2[r] = sq * 0.5f;
  uint4 u;
  u.x = f2bf(a.x) | (f2bf(a.y) << 16);
  u.y = f2bf(a.z) | (f2bf(a.w) << 16);
  u.z = f2bf(b.x) | (f2bf(b.y) << 16);
  u.w = f2bf(b.z) | (f2bf(b.w) << 16);
  tkbf[(size_t)(r >> 6) * 512 + (r & 63) * 8 + (c ^ (r & 7))] = u;
}

// ---------------- Kernel 1a: sampled bf16 d2' via MFMA -> u16 store ----------------
// 256 blocks: (chunk of 128 rows) x (2 query tiles). d2' = 2*(tnh - dot);
// u16 = clamp((d2' + 128) * 256). Ordering per query == exact d2 ordering.
__global__ __launch_bounds__(512, 4) void qthresh_mfma(
    const uint4* __restrict__ tkbf, const float* __restrict__ keys,
    const float* __restrict__ tnh2, unsigned short* __restrict__ dsamp) {
  __shared__ __align__(16) uint4 bstage[2][512];
  __shared__ float tnh_lds[128];
  int tid = threadIdx.x;
  int qt = blockIdx.x & 1;
  int chunk = blockIdx.x >> 1;       // 0..127
  int qbase = qt * QTILE;
  int rstart = chunk * 128;
  if (tid < 128) tnh_lds[tid] = tnh2[rstart + tid];
  int lane = tid & 63, wq = tid >> 6, l15 = lane & 15, quad = lane >> 4;
  short8 afrag[4][2];
  #pragma unroll
  for (int mt = 0; mt < 4; ++mt) {
    const float* kp = keys + (size_t)(qbase + wq * 64 + mt * 16 + l15) * 64 + quad * 8;
    #pragma unroll
    for (int s = 0; s < 2; ++s) {
      float4 x = *(const float4*)(kp + s * 32);
      float4 y = *(const float4*)(kp + s * 32 + 4);
      short8 a;
      a[0] = (short)f2bf(x.x); a[1] = (short)f2bf(x.y);
      a[2] = (short)f2bf(x.z); a[3] = (short)f2bf(x.w);
      a[4] = (short)f2bf(y.x); a[5] = (short)f2bf(y.y);
      a[6] = (short)f2bf(y.z); a[7] = (short)f2bf(y.w);
      afrag[mt][s] = a;
    }
  }
  const uint4* gbase = tkbf + (size_t)(rstart >> 6) * 512;
  __builtin_amdgcn_global_load_lds((g_u32*)(gbase + tid),
                                   (l_u32*)(&bstage[0][wq * 64]), 16, 0, 0);
  __syncthreads();
  f32x4 zero4 = {0.f, 0.f, 0.f, 0.f};
  for (int it = 0; it < 2; ++it) {
    if (it == 0)
      __builtin_amdgcn_global_load_lds((g_u32*)(gbase + 512 + tid),
                                       (l_u32*)(&bstage[1][wq * 64]), 16, 0, 0);
    const unsigned char* buf = (const unsigned char*)bstage[it & 1];
    #pragma unroll
    for (int half = 0; half < 2; ++half) {
      short8 b[2][2];
      #pragma unroll
      for (int tt = 0; tt < 2; ++tt) {
        int nloc = half * 32 + tt * 16 + l15;
        #pragma unroll
        for (int s = 0; s < 2; ++s) {
          int c = s * 4 + quad;
          unsigned addr = (unsigned)(nloc * 128 + ((c ^ (nloc & 7)) << 4));
          b[tt][s] = *(const short8*)(buf + addr);
        }
      }
      f32x4 acc[4][2];
      #pragma unroll
      for (int mt = 0; mt < 4; ++mt)
        #pragma unroll
        for (int tt = 0; tt < 2; ++tt) {
          f32x4 a0 = __builtin_amdgcn_mfma_f32_16x16x32_bf16(afrag[mt][0], b[tt][0], zero4, 0, 0, 0);
          acc[mt][tt] = __builtin_amdgcn_mfma_f32_16x16x32_bf16(afrag[mt][1], b[tt][1], a0, 0, 0, 0);
        }
      #pragma unroll
      for (int tt = 0; tt < 2; ++tt) {
        int rloc = it * 64 + half * 32 + tt * 16 + l15;
        float tnh = tnh_lds[rloc];
        int n = rstart + rloc;
        #pragma unroll
        for (int mt = 0; mt < 4; ++mt) {
          #pragma unroll
          for (int r = 0; r < 4; ++r) {
            int ql = wq * 64 + mt * 16 + quad * 4 + r;
            // u16 = (2*(tnh-acc) + 128)*256 = (tnh-acc)*512 + 32768
            int u = (int)fmaf(tnh - acc[mt][tt][r], 512.f, 32768.f);
            u = u < 0 ? 0 : (u > 65535 ? 65535 : u);
            dsamp[(size_t)(qbase + ql) * S_SAMP + n] = (unsigned short)u;
          }
        }
      }
    }
    __syncthreads();
  }
}

// ---------------- Kernel 1b: per-query T-th smallest -> halved threshold ----------------
__global__ __launch_bounds__(256) void qthresh_scan(
    const unsigned short* __restrict__ dsamp, float* __restrict__ thrh,
    int* __restrict__ cnt) {
  int q = blockIdx.x;
  __shared__ unsigned hist[512];
  int tid = threadIdx.x;
  hist[tid] = 0u; hist[tid + 256] = 0u;
  __syncthreads();
  const unsigned short* dp = dsamp + (size_t)q * S_SAMP;
  for (int i = tid; i < S_SAMP; i += 256) atomicAdd(&hist[dp[i] >> 7], 1u);
  __syncthreads();
  if (tid == 0) {
    unsigned cum = 0; int bstar = 511;
    for (int b = 0; b < 512; ++b) {
      cum += hist[b];
      if (cum >= (unsigned)T_SAMP) { bstar = b; break; }
    }
    // bin width 0.5 in d2' space; thr = binUpper + margin; store thr/2
    float thr = (float)(bstar + 1) * 0.5f - 128.f + MARGIN_T;
    thrh[q] = 0.5f * thr;
    cnt[q] = 0;
  }
}

// ---------------- Kernel 2a: async-staged bf16 MFMA filter (qn-free epilogue) ----------------
// hit <=> tnh - acc < thrh[ql]; payload d2q = (tnh-acc)*32 + 2048 (13 bits).
__global__ __launch_bounds__(512, 4) void filter_mfma_fast(
    const uint4* __restrict__ tkbf, const float* __restrict__ keys,
    const float* __restrict__ tnh2, const float* __restrict__ thrh,
    int* __restrict__ cnt, unsigned* __restrict__ candi, int C, int cap) {
  __shared__ __align__(16) uint4 bstage[2][512];          // 16 KB dbuf
  __shared__ float tnh_lds[RPB];                          // 4 KB
  __shared__ float thr_lds[QTILE];                        // 2 KB (halved thr)
  __shared__ unsigned scnt[QTILE];                        // 2 KB
  __shared__ unsigned sbuf[QTILE * SDEPTH];               // 12 KB

  int tid = threadIdx.x;
  int qt = blockIdx.x & 1;
  int chunk = blockIdx.x >> 1;
  int qbase = qt * QTILE;
  int rstart = chunk * RPB;

  tnh_lds[tid] = tnh2[rstart + tid];
  tnh_lds[tid + 512] = tnh2[rstart + tid + 512];
  thr_lds[tid] = thrh[qbase + tid];
  scnt[tid] = 0u;

  int lane = tid & 63, wq = tid >> 6, l15 = lane & 15, quad = lane >> 4;

  short8 afrag[4][2];
  #pragma unroll
  for (int mt = 0; mt < 4; ++mt) {
    const float* kp = keys + (size_t)(qbase + wq * 64 + mt * 16 + l15) * 64 + quad * 8;
    #pragma unroll
    for (int s = 0; s < 2; ++s) {
      float4 x = *(const float4*)(kp + s * 32);
      float4 y = *(const float4*)(kp + s * 32 + 4);
      short8 a;
      a[0] = (short)f2bf(x.x); a[1] = (short)f2bf(x.y);
      a[2] = (short)f2bf(x.z); a[3] = (short)f2bf(x.w);
      a[4] = (short)f2bf(y.x); a[5] = (short)f2bf(y.y);
      a[6] = (short)f2bf(y.z); a[7] = (short)f2bf(y.w);
      afrag[mt][s] = a;
    }
  }

  const uint4* gbase = tkbf + (size_t)(rstart >> 6) * 512;
  __builtin_amdgcn_global_load_lds((g_u32*)(gbase + tid),
                                   (l_u32*)(&bstage[0][wq * 64]), 16, 0, 0);
  __syncthreads();

  float hmax[4];
  #pragma unroll
  for (int mt = 0; mt < 4; ++mt) {
    float h0 = thr_lds[wq * 64 + mt * 16 + quad * 4 + 0];
    float h1 = thr_lds[wq * 64 + mt * 16 + quad * 4 + 1];
    float h2 = thr_lds[wq * 64 + mt * 16 + quad * 4 + 2];
    float h3 = thr_lds[wq * 64 + mt * 16 + quad * 4 + 3];
    hmax[mt] = fmaxf(fmaxf(h0, h1), fmaxf(h2, h3));
  }

  f32x4 zero4 = {0.f, 0.f, 0.f, 0.f};
  const int ITERS = RPB / 64;   // 16

  for (int it = 0; it < ITERS; ++it) {
    if (it + 1 < ITERS) {
      __builtin_amdgcn_global_load_lds((g_u32*)(gbase + (size_t)(it + 1) * 512 + tid),
                                       (l_u32*)(&bstage[(it + 1) & 1][wq * 64]), 16, 0, 0);
    }
    const unsigned char* buf = (const unsigned char*)bstage[it & 1];
    #pragma unroll
    for (int half = 0; half < 2; ++half) {
      short8 b[2][2];
      #pragma unroll
      for (int tt = 0; tt < 2; ++tt) {
        int nloc = half * 32 + tt * 16 + l15;
        #pragma unroll
        for (int s = 0; s < 2; ++s) {
          int c = s * 4 + quad;
          unsigned addr = (unsigned)(nloc * 128 + ((c ^ (nloc & 7)) << 4));
          b[tt][s] = *(const short8*)(buf + addr);
        }
      }
      f32x4 acc[4][2];
      #pragma unroll
      for (int mt = 0; mt < 4; ++mt)
        #pragma unroll
        for (int tt = 0; tt < 2; ++tt) {
          f32x4 a0 = __builtin_amdgcn_mfma_f32_16x16x32_bf16(afrag[mt][0], b[tt][0], zero4, 0, 0, 0);
          acc[mt][tt] = __builtin_amdgcn_mfma_f32_16x16x32_bf16(afrag[mt][1], b[tt][1], a0, 0, 0, 0);
        }
      #pragma unroll
      for (int tt = 0; tt < 2; ++tt) {
        int rloc = it * 64 + half * 32 + tt * 16 + l15;
        float tnh = tnh_lds[rloc];
        int n = rstart + rloc;
        #pragma unroll
        for (int mt = 0; mt < 4; ++mt) {
          float mx4 = fmaxf(fmaxf(acc[mt][tt][0], acc[mt][tt][1]),
                            fmaxf(acc[mt][tt][2], acc[mt][tt][3]));
          if (__builtin_expect(mx4 + hmax[mt] > tnh, 0)) {
            #pragma unroll
            for (int r = 0; r < 4; ++r) {
              int ql = wq * 64 + mt * 16 + quad * 4 + r;
              float t = tnh - acc[mt][tt][r];
              if (t < thr_lds[ql] && n < C) {
                int d2q = (int)fmaf(t, 32.f, 2048.f);
                d2q = d2q < 0 ? 0 : (d2q > 8191 ? 8191 : d2q);
                unsigned v = ((unsigned)d2q << 19) | (unsigned)n;
                unsigned p = atomicAdd(&scnt[ql], 1u);
                if (p < SDEPTH) {
                  sbuf[ql * SDEPTH + p] = v;
                } else {
                  int g = atomicAdd(&cnt[qbase + ql], 1);
                  if (g < cap) candi[(size_t)(qbase + ql) * cap + g] = v;
                }
              }
            }
          }
        }
      }
    }
    __syncthreads();
  }
  int m = (int)scnt[tid];
  if (m > SDEPTH) m = SDEPTH;
  if (m > 0) {
    int base = atomicAdd(&cnt[qbase + tid], m);
    for (int j = 0; j < m; ++j) {
      int g = base + j;
      if (g < cap) candi[(size_t)(qbase + tid) * cap + g] = sbuf[tid * SDEPTH + j];
    }
  }
}

// ---------------- FALLBACK kernels (R9 path; only if workspace too small) ----------------
__global__ __launch_bounds__(256) void qthresh_fb(
    const float* __restrict__ keys, const float* __restrict__ tk,
    float* __restrict__ thr, float* __restrict__ qnorm, int C) {
  int q0 = blockIdx.x * FQB;
  __shared__ __align__(16) float kq[FQB * 64];
  __shared__ unsigned hist[FQB][NBINS];
  __shared__ float qn4[FQB];
  int tid = threadIdx.x;
  for (int i = tid; i < FQB * 64; i += 256) kq[i] = keys[(size_t)q0 * 64 + i];
  for (int i = tid; i < FQB * NBINS; i += 256) (&hist[0][0])[i] = 0u;
  __syncthreads();
  if (tid < FQB) {
    float s = 0.f;
    for (int j = 0; j < 64; ++j) { float v = kq[tid * 64 + j]; s += v * v; }
    qn4[tid] = s;
  }
  __syncthreads();
  int kc = tid & 3;
  const float4* kq4 = (const float4*)kq;
  float4 kf[FQB][4];
  #pragma unroll
  for (int jq = 0; jq < FQB; ++jq)
    #pragma unroll
    for (int u = 0; u < 4; ++u) kf[jq][u] = kq4[jq * 16 + kc * 4 + u];
  int S = FSAMPLE < C ? FSAMPLE : C;
  for (int r = tid >> 2; r < S; r += 64) {
    const float4* trow = (const float4*)(tk + (size_t)r * 64 + kc * 16);
    float4 t0 = trow[0], t1 = trow[1], t2 = trow[2], t3 = trow[3];
    float tn = t0.x * t0.x + t0.y * t0.y + t0.z * t0.z + t0.w * t0.w
             + t1.x * t1.x + t1.y * t1.y + t1.z * t1.z + t1.w * t1.w
             + t2.x * t2.x + t2.y * t2.y + t2.z * t2.z + t2.w * t2.w
             + t3.x * t3.x + t3.y * t3.y + t3.z * t3.z + t3.w * t3.w;
    tn += __shfl_xor(tn, 1); tn += __shfl_xor(tn, 2);
    float dot[FQB];
    #pragma unroll
    for (int jq = 0; jq < FQB; ++jq) {
      float s = kf[jq][0].x * t0.x + kf[jq][0].y * t0.y + kf[jq][0].z * t0.z + kf[jq][0].w * t0.w
              + kf[jq][1].x * t1.x + kf[jq][1].y * t1.y + kf[jq][1].z * t1.z + kf[jq][1].w * t1.w
              + kf[jq][2].x * t2.x + kf[jq][2].y * t2.y + kf[jq][2].z * t2.z + kf[jq][2].w * t2.w
              + kf[jq][3].x * t3.x + kf[jq][3].y * t3.y + kf[jq][3].z * t3.z + kf[jq][3].w * t3.w;
      s += __shfl_xor(s, 1); s += __shfl_xor(s, 2);
      dot[jq] = s;
    }
    if (kc == 0) {
      #pragma unroll
      for (int jq = 0; jq < FQB; ++jq) {
        float d2 = qn4[jq] + tn - 2.f * dot[jq];
        int b = (int)d2;
        b = b < 0 ? 0 : (b > NBINS - 1 ? NBINS - 1 : b);
        atomicAdd(&hist[jq][b], 1u);
      }
    }
  }
  __syncthreads();
  if (tid < FQB) {
    unsigned cum = 0; int bstar = NBINS - 1;
    for (int b = 0; b < NBINS; ++b) {
      cum += hist[tid][b];
      if (cum >= (unsigned)FTARGET) { bstar = b; break; }
    }
    thr[q0 + tid] = (float)(bstar + 1) + FMARGIN - qn4[tid];
    qnorm[q0 + tid] = qn4[tid];
  }
}

__global__ __launch_bounds__(512, 4) void filter_fb(
    const float* __restrict__ keys, const float* __restrict__ tk,
    const float* __restrict__ thr, const float* __restrict__ qnorm,
    int* __restrict__ cnt, unsigned* __restrict__ candi, int C, int cap) {
  __shared__ float tnstage[64];
  __shared__ float thr_lds[QTILE];
  __shared__ float qn_lds[QTILE];
  __shared__ unsigned scnt[QTILE];
  __shared__ unsigned sbuf[QTILE * SDEPTH];
  __shared__ __align__(16) unsigned char bstage[64 * 128];
  int tid = threadIdx.x;
  int qt = blockIdx.x & 1;
  int chunk = blockIdx.x >> 1;
  int qbase = qt * QTILE;
  int rstart = chunk * RPB;
  thr_lds[tid] = thr[qbase + tid];
  qn_lds[tid] = qnorm[qbase + tid];
  scnt[tid] = 0u;
  int lane = tid & 63, wq = tid >> 6, l15 = lane & 15, quad = lane >> 4;
  short8 afrag[4][2];
  #pragma unroll
  for (int mt = 0; mt < 4; ++mt) {
    const float* kp = keys + (size_t)(qbase + wq * 64 + mt * 16 + l15) * 64 + quad * 8;
    #pragma unroll
    for (int s = 0; s < 2; ++s) {
      float4 x = *(const float4*)(kp + s * 32);
      float4 y = *(const float4*)(kp + s * 32 + 4);
      short8 a;
      a[0] = (short)f2bf(x.x); a[1] = (short)f2bf(x.y);
      a[2] = (short)f2bf(x.z); a[3] = (short)f2bf(x.w);
      a[4] = (short)f2bf(y.x); a[5] = (short)f2bf(y.y);
      a[6] = (short)f2bf(y.z); a[7] = (short)f2bf(y.w);
      afrag[mt][s] = a;
    }
  }
  __syncthreads();
  float hq[4];
  #pragma unroll
  for (int mt = 0; mt < 4; ++mt) {
    float h0 = thr_lds[wq * 64 + mt * 16 + quad * 4 + 0];
    float h1 = thr_lds[wq * 64 + mt * 16 + quad * 4 + 1];
    float h2 = thr_lds[wq * 64 + mt * 16 + quad * 4 + 2];
    float h3 = thr_lds[wq * 64 + mt * 16 + quad * 4 + 3];
    hq[mt] = fmaxf(fmaxf(h0, h1), fmaxf(h2, h3));
  }
  int srow = tid >> 3, scol = tid & 7;
  unsigned sbyte = (unsigned)(srow * 128 + ((scol ^ (srow & 7)) << 4));
  const int ITERS = RPB / 64;
  int r0 = rstart + srow; if (r0 > C - 1) r0 = C - 1;
  float4 pa = *(const float4*)(tk + (size_t)r0 * 64 + scol * 8);
  float4 pb = *(const float4*)(tk + (size_t)r0 * 64 + scol * 8 + 4);
  f32x4 zero4 = {0.f, 0.f, 0.f, 0.f};
  for (int it = 0; it < ITERS; ++it) {
    float part = pa.x * pa.x + pa.y * pa.y + pa.z * pa.z + pa.w * pa.w
               + pb.x * pb.x + pb.y * pb.y + pb.z * pb.z + pb.w * pb.w;
    part += __shfl_xor(part, 1); part += __shfl_xor(part, 2); part += __shfl_xor(part, 4);
    if ((tid & 7) == 0) tnstage[srow] = part;
    uint4 u;
    u.x = f2bf(pa.x) | (f2bf(pa.y) << 16);
    u.y = f2bf(pa.z) | (f2bf(pa.w) << 16);
    u.z = f2bf(pb.x) | (f2bf(pb.y) << 16);
    u.w = f2bf(pb.z) | (f2bf(pb.w) << 16);
    *(uint4*)(bstage + sbyte) = u;
    __syncthreads();
    if (it + 1 < ITERS) {
      int rn = rstart + (it + 1) * 64 + srow; if (rn > C - 1) rn = C - 1;
      pa = *(const float4*)(tk + (size_t)rn * 64 + scol * 8);
      pb = *(const float4*)(tk + (size_t)rn * 64 + scol * 8 + 4);
    }
    #pragma unroll
    for (int half = 0; half < 2; ++half) {
      short8 b[2][2];
      #pragma unroll
      for (int tt = 0; tt < 2; ++tt) {
        int nloc = half * 32 + tt * 16 + l15;
        #pragma unroll
        for (int s = 0; s < 2; ++s) {
          int c = s * 4 + quad;
          unsigned addr = (unsigned)(nloc * 128 + ((c ^ (nloc & 7)) << 4));
          b[tt][s] = *(const short8*)(bstage + addr);
        }
      }
      f32x4 acc[4][2];
      #pragma unroll
      for (int mt = 0; mt < 4; ++mt)
        #pragma unroll
        for (int tt = 0; tt < 2; ++tt) {
          f32x4 a0 = __builtin_amdgcn_mfma_f32_16x16x32_bf16(afrag[mt][0], b[tt][0], zero4, 0, 0, 0);
          acc[mt][tt] = __builtin_amdgcn_mfma_f32_16x16x32_bf16(afrag[mt][1], b[tt][1], a0, 0, 0, 0);
        }
      #pragma unroll
      for (int tt = 0; tt < 2; ++tt) {
        float tn = tnstage[half * 32 + tt * 16 + l15];
        int n = rstart + it * 64 + half * 32 + tt * 16 + l15;
        #pragma unroll
        for (int mt = 0; mt < 4; ++mt) {
          float d0 = fmaf(-2.f, acc[mt][tt][0], tn);
          float d1 = fmaf(-2.f, acc[mt][tt][1], tn);
          float d2 = fmaf(-2.f, acc[mt][tt][2], tn);
          float d3 = fmaf(-2.f, acc[mt][tt][3], tn);
          float mn4 = fminf(fminf(d0, d1), fminf(d2, d3));
          if (mn4 < hq[mt]) {
            float dd[4] = {d0, d1, d2, d3};
            #pragma unroll
            for (int r = 0; r < 4; ++r) {
              int ql = wq * 64 + mt * 16 + quad * 4 + r;
              if (dd[r] < thr_lds[ql] && n < C) {
                float d2f = dd[r] + qn_lds[ql];
                int d2q = (int)(d2f * 16.f);
                d2q = d2q < 0 ? 0 : (d2q > 8191 ? 8191 : d2q);
                unsigned v = ((unsigned)d2q << 19) | (unsigned)n;
                unsigned p = atomicAdd(&scnt[ql], 1u);
                if (p < SDEPTH) sbuf[ql * SDEPTH + p] = v;
                else {
                  int g = atomicAdd(&cnt[qbase + ql], 1);
                  if (g < cap) candi[(size_t)(qbase + ql) * cap + g] = v;
                }
              }
            }
          }
        }
      }
    }
    __syncthreads();
  }
  int m = (int)scnt[tid];
  if (m > SDEPTH) m = SDEPTH;
  if (m > 0) {
    int base = atomicAdd(&cnt[qbase + tid], m);
    for (int j = 0; j < m; ++j) {
      int g = base + j;
      if (g < cap) candi[(size_t)(qbase + tid) * cap + g] = sbuf[tid * SDEPTH + j];
    }
  }
}

// ---------------- Kernel 3: select (payload-order agnostic; fp32 rescore) ----------------
__global__ __launch_bounds__(256) void select_kernel(
    const float* __restrict__ keys, const float* __restrict__ tk,
    const float* __restrict__ tv, const int* __restrict__ cnt,
    const unsigned* __restrict__ candi, float* __restrict__ out, int cap) {
  int q = blockIdx.x;
  __shared__ unsigned cvl[CVL];
  __shared__ unsigned hist[NBINS];
  __shared__ unsigned wsum[4];
  __shared__ unsigned minq_sh;
  __shared__ int b50_sh;
  __shared__ int lidx[LW];
  __shared__ unsigned ed2[LW];
  __shared__ int m_sh;
  __shared__ float redw[4], redwv[4];
  int tid = threadIdx.x;
  int lane = tid & 63;
  int wid = tid >> 6;
  int n = cnt[q];
  if (n > cap) n = cap;
  hist[tid] = 0u;
  if (tid == 0) { minq_sh = 0xffffffffu; b50_sh = NBINS - 1; m_sh = 0; }
  __syncthreads();
  const unsigned* cv = candi + (size_t)q * cap;
  unsigned mn = 0xffffffffu;
  for (int i = tid; i < n; i += 256) {
    unsigned v = cv[i];
    if (i < CVL) cvl[i] = v;
    unsigned d = v >> 19; if (d < mn) mn = d;
  }
  #pragma unroll
  for (int off = 1; off < 64; off <<= 1) { unsigned o = __shfl_xor(mn, off); if (o < mn) mn = o; }
  if (lane == 0) atomicMin(&minq_sh, mn);
  __syncthreads();
  unsigned base = minq_sh;
  for (int i = tid; i < n; i += 256) {
    unsigned v = (i < CVL) ? cvl[i] : cv[i];
    unsigned d = (v >> 19) - base;
    unsigned b = d >> 1; if (b > NBINS - 1) b = NBINS - 1;
    atomicAdd(&hist[b], 1u);
  }
  __syncthreads();
  unsigned h = hist[tid];
  unsigned p = h;
  #pragma unroll
  for (int off = 1; off < 64; off <<= 1) {
    unsigned v = __shfl_up(p, off);
    if (lane >= off) p += v;
  }
  if (lane == 63) wsum[wid] = p;
  __syncthreads();
  unsigned add = 0;
  for (int w2 = 0; w2 < wid; ++w2) add += wsum[w2];
  p += add;
  if (p >= (unsigned)K_NEIGH && p - h < (unsigned)K_NEIGH) b50_sh = tid;
  __syncthreads();
  unsigned Tq = base + (((unsigned)(b50_sh + 1)) << 1) + MARGIN_Q;
  for (int i = tid; i < n; i += 256) {
    unsigned v = (i < CVL) ? cvl[i] : cv[i];
    if ((v >> 19) <= Tq) {
      int p2 = atomicAdd(&m_sh, 1);
      if (p2 < LW) lidx[p2] = (int)(v & 0x7ffffu);
    }
  }
  __syncthreads();
  int m = m_sh; if (m > LW) m = LW;
  float kqv = keys[(size_t)q * 64 + lane];
  for (int i0 = wid * 4; i0 < m; i0 += 16) {
    int mm = m - i0; if (mm > 4) mm = 4;
    int idx[4]; float t[4];
    for (int u = 0; u < mm; ++u) idx[u] = lidx[i0 + u];
    for (int u = 0; u < mm; ++u) t[u] = tk[(size_t)idx[u] * 64 + lane];
    for (int u = 0; u < mm; ++u) {
      float d = t[u] - kqv;
      float s = d * d;
      #pragma unroll
      for (int off = 1; off < 64; off <<= 1) s += __shfl_xor(s, off);
      if (lane == 0) ed2[i0 + u] = __float_as_uint(s);
    }
  }
  __syncthreads();
  float accw = 0.f, accwv = 0.f;
  for (int i = tid; i < m; i += 256) {
    unsigned long long key = ((unsigned long long)ed2[i] << 19) | (unsigned)lidx[i];
    int rank = 0;
    for (int j = 0; j < m; ++j) {
      unsigned long long kj = ((unsigned long long)ed2[j] << 19) | (unsigned)lidx[j];
      rank += (kj < key) ? 1 : 0;
    }
    if (rank < K_NEIGH) {
      float d2 = __uint_as_float(ed2[i]);
      float w = 1.f / (d2 + DELTA_SMOOTH);
      accw += w;
      accwv += w * tv[lidx[i]];
    }
  }
  #pragma unroll
  for (int off = 1; off < 64; off <<= 1) {
    accw += __shfl_xor(accw, off);
    accwv += __shfl_xor(accwv, off);
  }
  if (lane == 0) { redw[wid] = accw; redwv[wid] = accwv; }
  __syncthreads();
  if (tid == 0) {
    float sw = redw[0] + redw[1] + redw[2] + redw[3];
    float swv = redwv[0] + redwv[1] + redwv[2] + redwv[3];
    out[q] = swv / sw;
  }
}

extern "C" void kernel_launch(void* const* d_in, const int* in_sizes, int n_in,
                              void* d_out, int out_size, void* d_ws, size_t ws_size,
                              hipStream_t stream) {
  const float* keys = (const float*)d_in[0];   // [B,64]
  const float* tk   = (const float*)d_in[1];   // [C,64]
  const float* tv   = (const float*)d_in[2];   // [C]
  float* out = (float*)d_out;
  int B = in_sizes[0] / 64;   // 1024
  int C = in_sizes[2];        // 500000 (< 2^19 for packing)

  int nchunks = (C + RPB - 1) / RPB;
  int padded = nchunks * RPB;

  char* w = (char*)d_ws;
  float* thrh = (float*)w;  w += (size_t)B * 4;   // fast: thr/2 | fb: thr
  float* qnfb = (float*)w;  w += (size_t)B * 4;   // fallback qn
  int*   cnt  = (int*)w;    w += (size_t)B * 4;
  size_t fixed = (size_t)(w - (char*)d_ws);

  size_t tk_bytes = (size_t)padded * 128 + (size_t)padded * 4;
  size_t dsamp_bytes = (size_t)S_SAMP * (size_t)B * 2;   // 33.5 MB
  size_t region = ws_size > fixed + tk_bytes ? ws_size - fixed - tk_bytes : 0;
  bool fast = region >= dsamp_bytes && region >= 2048ull * (size_t)B * 4;

  if (fast) {
    uint4* tkbf = (uint4*)w;              w += (size_t)padded * 128;
    float* tnh2 = (float*)w;              w += (size_t)padded * 4;
    // dsamp and candi alias the same region (sequential lifetimes)
    unsigned short* dsamp = (unsigned short*)w;
    unsigned* candi = (unsigned*)w;
    int cap = (int)(region / (4ull * (size_t)B));
    if (cap > MAXCAP) cap = MAXCAP;
    convert_kernel<<<(padded * 8 + 255) / 256, 256, 0, stream>>>(tk, tkbf, tnh2, C, padded);
    qthresh_mfma<<<256, 512, 0, stream>>>(tkbf, keys, tnh2, dsamp);
    qthresh_scan<<<B, 256, 0, stream>>>(dsamp, thrh, cnt);   // also zeros cnt
    filter_mfma_fast<<<nchunks * 2, 512, 0, stream>>>(tkbf, keys, tnh2, thrh,
                                                      cnt, candi, C, cap);
    select_kernel<<<B, 256, 0, stream>>>(keys, tk, tv, cnt, candi, out, cap);
  } else {
    unsigned* candi = (unsigned*)w;
    int cap = (int)((ws_size - fixed) / (4ull * (size_t)B));
    if (cap > MAXCAP) cap = MAXCAP;
    if (cap < 1) cap = 1;
    hipMemsetAsync(cnt, 0, (size_t)B * 4, stream);
    qthresh_fb<<<B / FQB, 256, 0, stream>>>(keys, tk, thrh, qnfb, C);
    filter_fb<<<nchunks * 2, 512, 0, stream>>>(keys, tk, thrh, qnfb,
                                               cnt, candi, C, cap);
    select_kernel<<<B, 256, 0, stream>>>(keys, tk, tv, cnt, candi, out, cap);
  }
}